// Round 1
// baseline (459.747 us; speedup 1.0000x reference)
//
#include <hip/hip_runtime.h>
#include <hip/hip_bf16.h>
#include <math.h>

#define N_NODES 50000
#define E_EDGES 400000
#define EN_TOT  (E_EDGES + N_NODES)
#define F_IN    128
#define HC      384
#define CLASSES 40

typedef short short8 __attribute__((ext_vector_type(8)));
typedef float floatx4 __attribute__((ext_vector_type(4)));
typedef float floatx2 __attribute__((ext_vector_type(2)));
typedef unsigned int uint;

__device__ __forceinline__ float bf2f(unsigned short u) {
  union { unsigned int i; float f; } x; x.i = ((unsigned int)u) << 16; return x.f;
}
__device__ __forceinline__ unsigned short f2bf(float f) {
  union { float f; unsigned int i; } x; x.f = f;
  unsigned int r = x.i + 0x7fffu + ((x.i >> 16) & 1u);
  return (unsigned short)(r >> 16);
}
__device__ __forceinline__ float fin(float v) {        // NaN/Inf -> 0 (no-op on healthy path)
  return (fabsf(v) < 1e30f) ? v : 0.f;
}
__device__ __forceinline__ float rdw(const void* p, int idx, int fp32) {
  return fp32 ? ((const float*)p)[idx] : bf2f(((const unsigned short*)p)[idx]);
}

#if __has_builtin(__builtin_amdgcn_exp2f)
#define EXP2F(x) __builtin_amdgcn_exp2f(x)
#else
#define EXP2F(x) exp2f(x)
#endif

// 16-lane sum broadcast. DPP row size = 16 on gfx9 lineage, so quad_perm /
// row_half_mirror / row_mirror all stay inside a 16-lane group: pure-VALU
// v_add_f32_dpp (GCNDPPCombine fuses mov_dpp+add) replaces ds_swizzle+add.
#if __has_builtin(__builtin_amdgcn_update_dpp)
#define DPP_ADD(w, ctrl) \
  (w += __int_as_float(__builtin_amdgcn_update_dpp(0, __float_as_int(w), ctrl, 0xf, 0xf, true)))
#define REDUCE16(w) do { DPP_ADD(w, 0xB1); DPP_ADD(w, 0x4E); DPP_ADD(w, 0x141); DPP_ADD(w, 0x140); } while (0)
#else
#define REDUCE16(w) do { w += __shfl_xor(w, 1); w += __shfl_xor(w, 2); \
                         w += __shfl_xor(w, 4); w += __shfl_xor(w, 8); } while (0)
#endif

// ---------------- dtype detector (kept: auto-handles bf16-input datasets) ----------
__global__ void k_detect(const unsigned short* __restrict__ x, int* __restrict__ flag) {
  int L = threadIdx.x;
  int sane = 0;
#pragma unroll
  for (int i = 0; i < 4; ++i) {
    unsigned short u = x[(size_t)(L * 4 + i) * 2];
    unsigned int mag = u & 0x7FFFu;
    unsigned int e   = (u >> 7) & 0xFFu;
    if (mag == 0u || (e >= 96u && e <= 159u)) sane++;
  }
  sane += __shfl_xor(sane, 1);
  sane += __shfl_xor(sane, 2);
  sane += __shfl_xor(sane, 4);
  sane += __shfl_xor(sane, 8);
  sane += __shfl_xor(sane, 16);
  sane += __shfl_xor(sane, 32);
  if (L == 0) flag[0] = (sane < 179) ? 1 : 0;   // 1 => inputs are fp32
}

__global__ void k_sentinel(float* out, int n) {
  int i = blockIdx.x * 256 + threadIdx.x;
  if (i < n) out[i] = 111.0f;
}

// ---------------- CSR build ----------------
__global__ void k_zero2(int* p0, int* p1, int n) {
  int i = blockIdx.x * 256 + threadIdx.x;
  if (i < n) { p0[i] = 0; p1[i] = 0; }
}

__global__ void k_count(const int* __restrict__ ei, int* __restrict__ counts) {
  int e = blockIdx.x * 256 + threadIdx.x;
  if (e >= EN_TOT) return;
  int dst = (e < E_EDGES) ? ei[E_EDGES + e] : (e - E_EDGES);
  if ((unsigned)dst < N_NODES) atomicAdd(&counts[dst], 1);
}

// hierarchical scan
__global__ void k_scan1(const int* __restrict__ counts, int* __restrict__ row_start,
                        int* __restrict__ bsum) {
  int b = blockIdx.x, tid = threadIdx.x;
  int i = b * 1024 + tid;
  int v = (i < N_NODES) ? counts[i] : 0;
  int lane = tid & 63, w = tid >> 6;
  int x = v;
#pragma unroll
  for (int d = 1; d < 64; d <<= 1) { int t = __shfl_up(x, d); if (lane >= d) x += t; }
  __shared__ int wsum[16];
  if (lane == 63) wsum[w] = x;
  __syncthreads();
  if (w == 0) {
    int y = (lane < 16) ? wsum[lane] : 0;
#pragma unroll
    for (int d = 1; d < 16; d <<= 1) { int t = __shfl_up(y, d); if (lane >= d) y += t; }
    if (lane < 16) wsum[lane] = y;
  }
  __syncthreads();
  if (w > 0) x += wsum[w - 1];
  if (i < N_NODES) row_start[i + 1] = x;
  if (tid == 1023) bsum[b] = x;
}
__global__ void k_scan2(int* bsum, int nb) {
  int lane = threadIdx.x;
  int x = (lane < nb) ? bsum[lane] : 0;
#pragma unroll
  for (int d = 1; d < 64; d <<= 1) { int t = __shfl_up(x, d); if (lane >= d) x += t; }
  if (lane < nb) bsum[lane] = x;
}
__global__ void k_scan3(int* __restrict__ row_start, const int* __restrict__ bsum) {
  int b = blockIdx.x, tid = threadIdx.x;
  int i = b * 1024 + tid;
  if (i >= N_NODES) return;
  int add = (b > 0) ? bsum[b - 1] : 0;
  row_start[i + 1] += add;
  if (i == 0) row_start[0] = 0;
}

__global__ void k_fill(const int* __restrict__ ei, const int* __restrict__ row_start,
                       int* __restrict__ cursor, int* __restrict__ csr_src) {
  int e = blockIdx.x * 256 + threadIdx.x;
  if (e >= EN_TOT) return;
  int src, dst;
  if (e < E_EDGES) { src = ei[e]; dst = ei[E_EDGES + e]; }
  else             { src = dst = e - E_EDGES; }
  if ((unsigned)dst >= N_NODES) return;
  int pos = atomicAdd(&cursor[dst], 1);
  int slot = row_start[dst] + pos;
  if ((unsigned)slot < EN_TOT) csr_src[slot] = src;
}

// ---------------- B packing into MFMA fragment order (N = NT*16 cols) ----------
__global__ void k_pack_b(const void* __restrict__ B, unsigned short* __restrict__ Bp,
                         int K, int NT, const int* __restrict__ flagp) {
  int N = NT * 16;
  int idx = blockIdx.x * 256 + threadIdx.x;
  if (idx >= K * N) return;
  int fp32 = flagp[0];
  int j  = idx & 7;
  int L  = (idx >> 3) & 63;
  int t  = idx >> 9;       // kt*NT + nt
  int nt = t % NT;
  int kt = t / NT;
  int k  = kt * 32 + ((L >> 4) * 8) + j;
  int n  = nt * 16 + (L & 15);
  float v = rdw(B, k * N + n, fp32);
  Bp[idx] = f2bf(fin(v));
}

// ---------------- GEMM, LDS-free: block = 4 waves, tile 64 rows x 384 cols ------
// Each wave owns 64 rows x 96 cols (acc[4][6]); every B fragment read (L2-hot,
// Bp is <=288KB so it lives in each XCD's L2) feeds FOUR MFMAs, so the old
// 1 ds_read_b128 : 1 MFMA LDS-pipe bottleneck (96 reads x ~12cy per block per
// kt vs 120cy of MFMA) and both per-kt barriers disappear. K-loop fully
// unrolled via template so the compiler pipelines kt+1 loads under kt MFMAs.
template<int NK, int AF>
__global__ __launch_bounds__(256, 2) void k_gemm(const void* __restrict__ A_,
                       const unsigned short* __restrict__ Bp,
                       unsigned short* __restrict__ C,
                       const int* __restrict__ flagp) {
  constexpr int K = NK * 32;
  int fp32 = AF ? flagp[0] : 0;
  int tid  = threadIdx.x;
  int wave = tid >> 6, lane = tid & 63;
  int m0   = blockIdx.x * 64;
  int kk   = (lane >> 4) * 8;
  int nt0  = wave * 6;
  int rowb = m0 + (lane & 15);
  int rc[4];
#pragma unroll
  for (int mf = 0; mf < 4; ++mf) {
    int r = rowb + mf * 16;
    rc[mf] = r < N_NODES ? r : N_NODES - 1;   // tail rows clamped, stores guarded
  }
  floatx4 acc[4][6];
#pragma unroll
  for (int mf = 0; mf < 4; ++mf)
#pragma unroll
    for (int n = 0; n < 6; ++n) acc[mf][n] = (floatx4){0.f, 0.f, 0.f, 0.f};

#pragma unroll
  for (int kt = 0; kt < NK; ++kt) {
    short8 af[4];
    if (fp32) {
      const float* Af = (const float*)A_ + (size_t)kt * 32 + kk;
#pragma unroll
      for (int mf = 0; mf < 4; ++mf) {
        const float* p = Af + (size_t)rc[mf] * K;
        floatx4 f0 = *(const floatx4*)p;
        floatx4 f1 = *(const floatx4*)(p + 4);
#pragma unroll
        for (int j = 0; j < 4; ++j) {
          af[mf][j]     = (short)f2bf(f0[j]);
          af[mf][4 + j] = (short)f2bf(f1[j]);
        }
      }
    } else {
      const unsigned short* Ab = (const unsigned short*)A_ + (size_t)kt * 32 + kk;
#pragma unroll
      for (int mf = 0; mf < 4; ++mf)
        af[mf] = *(const short8*)(Ab + (size_t)rc[mf] * K);
    }
    const short8* bp = (const short8*)Bp + ((size_t)(kt * 24 + nt0)) * 64 + lane;
    short8 bf[6];
#pragma unroll
    for (int n = 0; n < 6; ++n) bf[n] = bp[(size_t)n * 64];
#pragma unroll
    for (int n = 0; n < 6; ++n)
#pragma unroll
      for (int mf = 0; mf < 4; ++mf)
        acc[mf][n] = __builtin_amdgcn_mfma_f32_16x16x32_bf16(af[mf], bf[n], acc[mf][n], 0, 0, 0);
  }
  int qr = lane >> 4, ccol = lane & 15;
#pragma unroll
  for (int mf = 0; mf < 4; ++mf)
#pragma unroll
    for (int n = 0; n < 6; ++n)
#pragma unroll
      for (int r = 0; r < 4; ++r) {
        int orow = m0 + mf * 16 + qr * 4 + r;
        if (orow < N_NODES)
          C[(size_t)orow * HC + (nt0 + n) * 16 + ccol] = f2bf(fin(acc[mf][n][r]));
      }
}

// ---------------- MLP-1 via MFMA: C[M,32] = ELU(A[M,384] @ W3p + b3) ------------
__global__ void k_mlp1_mfma(const unsigned short* __restrict__ H2,
                            const unsigned short* __restrict__ Bp3,
                            const void* __restrict__ b3, float* __restrict__ H3,
                            const int* __restrict__ flagp) {
  int fp32 = flagp[0];
  int lane = threadIdx.x;
  int m0   = blockIdx.x * 16;
  int row  = m0 + (lane & 15);
  int kk   = (lane >> 4) * 8;
  floatx4 acc[2];
  acc[0] = (floatx4){0.f, 0.f, 0.f, 0.f};
  acc[1] = (floatx4){0.f, 0.f, 0.f, 0.f};
#pragma unroll
  for (int kt = 0; kt < 12; ++kt) {
    short8 af = *(const short8*)(H2 + (size_t)row * HC + kt * 32 + kk);
    const short8* bp = (const short8*)Bp3 + (size_t)kt * 2 * 64 + lane;
    acc[0] = __builtin_amdgcn_mfma_f32_16x16x32_bf16(af, bp[0],  acc[0], 0, 0, 0);
    acc[1] = __builtin_amdgcn_mfma_f32_16x16x32_bf16(af, bp[64], acc[1], 0, 0, 0);
  }
  int qr   = lane >> 4;
  int ccol = lane & 15;
#pragma unroll
  for (int nt = 0; nt < 2; ++nt)
#pragma unroll
    for (int r = 0; r < 4; ++r) {
      int col = nt * 16 + ccol;
      float s = acc[nt][r] + fin(rdw(b3, col, fp32));
      s = s > 0.f ? s : expm1f(s);
      H3[(size_t)(m0 + qr * 4 + r) * 32 + col] = fin(s);
    }
}

// ---------------- edge aggregation: wave per dst node, NO-MAX softmax ----------
// Softmax is shift-invariant; logits here are O(+-12), so exp without max-
// subtraction is safe; clamp is the overflow hard-stop only.
// Changes vs previous version (all VALU-issue cuts; kernel is VALU-bound at
// 85% VALUBusy / 0% MfmaUtil / 32% HBM):
//  - att weights pre-scaled by log2(e) once per node -> p = exp2(w), one
//    v_exp_f32, no per-edge mul; clamp +-126 (log2 domain) folds to v_med3.
//  - 16-lane logit reduce via v_add_f32_dpp butterfly (quad_perm xor1/xor2,
//    row_half_mirror, row_mirror) -> 4 VALU ops, zero LDS-pipe traffic,
//    no lgkmcnt stalls (was 4 ds_swizzle + 4 adds per head per edge).
//  - channel math in float2 ext-vectors -> v_pk_{add,mul,max,fma}_f32.
// Pair layout unchanged: lane L owns channels c = 2L + 128k + {0,1}, k=0..2;
// head(c) = (L>>4) + 4k -> 16-lane reduction groups (DPP row=16 aligned).
__global__ void k_edge(const unsigned short* __restrict__ XL, const unsigned short* __restrict__ XR,
                       const int* __restrict__ row_start, const int* __restrict__ csr_src,
                       const void* __restrict__ att, const void* __restrict__ bias,
                       unsigned short* __restrict__ H, const int* __restrict__ flagp) {
  int fp32 = flagp[0];
  int v = blockIdx.x;
  int L = threadIdx.x;
  floatx2 r2[3], a2[3];
  const uint* xr_row = (const uint*)(XR + (size_t)v * HC);
#pragma unroll
  for (int k = 0; k < 3; ++k) {
    uint rv = xr_row[L + 64 * k];
    r2[k].x = __uint_as_float(rv << 16);
    r2[k].y = __uint_as_float(rv & 0xffff0000u);
    int c = 2 * L + 128 * k;
    a2[k].x = fin(rdw(att, c,     fp32)) * 1.44269504088896f;   // fold log2(e)
    a2[k].y = fin(rdw(att, c + 1, fp32)) * 1.44269504088896f;
  }
  float l[3] = {0.f, 0.f, 0.f};
  floatx2 acc[3];
#pragma unroll
  for (int k = 0; k < 3; ++k) acc[k] = (floatx2){0.f, 0.f};
  int beg = row_start[v], end = row_start[v + 1];
  if (beg < 0) beg = 0;
  if (end > EN_TOT) end = EN_TOT;
  for (int e = beg; e < end; ++e) {
    int s = csr_src[e];
    if ((unsigned)s >= N_NODES) s = 0;
    const uint* xs = (const uint*)(XL + (size_t)s * HC);
    uint qa[3];
    qa[0] = xs[L];
    qa[1] = xs[L + 64];
    qa[2] = xs[L + 128];
#pragma unroll
    for (int k = 0; k < 3; ++k) {
      floatx2 sv;
      sv.x = __uint_as_float(qa[k] << 16);
      sv.y = __uint_as_float(qa[k] & 0xffff0000u);
      floatx2 t = sv + r2[k];                          // v_pk_add_f32
      t = __builtin_elementwise_max(t, t * 0.2f);      // pk_mul + pk_max = leaky_relu
      floatx2 dw = t * a2[k];                          // pk_mul
      float w = dw.x + dw.y;
      REDUCE16(w);                                     // 4x v_add_f32_dpp
      w = fminf(fmaxf(w, -126.f), 126.f);              // v_med3_f32 hard-stop
      float p = EXP2F(w);                              // v_exp_f32
      l[k] += p;
      floatx2 pv = {p, p};
      acc[k] += pv * sv;                               // v_pk_fma_f32
    }
  }
  uint* hr = (uint*)(H + (size_t)v * HC);
#pragma unroll
  for (int k = 0; k < 3; ++k) {
    int c = 2 * L + 128 * k;
    float inv = 1.f / fmaxf(l[k], 1e-30f);
    float o0 = acc[k].x * inv + fin(rdw(bias, c, fp32));
    float o1 = acc[k].y * inv + fin(rdw(bias, c + 1, fp32));
    o0 = o0 > 0.f ? o0 : expm1f(o0);
    o1 = o1 > 0.f ? o1 : expm1f(o1);
    hr[L + 64 * k] = (uint)f2bf(fin(o0)) | ((uint)f2bf(fin(o1)) << 16);
  }
}

// ---------------- MLP-2 + log_softmax ----------------
__global__ void k_mlp2(const float* __restrict__ H3, const void* __restrict__ W4,
                       const void* __restrict__ b4, float* __restrict__ out,
                       const int* __restrict__ flagp) {
  int fp32 = flagp[0];
  int v = blockIdx.x;
  int L = threadIdx.x;
  float logit = -1e30f;
  if (L < CLASSES) {
    logit = rdw(b4, L, fp32);
#pragma unroll
    for (int k = 0; k < 32; ++k)
      logit += H3[(size_t)v * 32 + k] * rdw(W4, k * CLASSES + L, fp32);
  }
  float mx = logit;
  for (int off = 1; off < 64; off <<= 1) mx = fmaxf(mx, __shfl_xor(mx, off));
  float ex = (L < CLASSES) ? __expf(logit - mx) : 0.f;
  ex = (ex == ex) ? ex : 0.f;
  float sm = ex;
  for (int off = 1; off < 64; off <<= 1) sm += __shfl_xor(sm, off);
  float ls = mx + logf(sm);
  if (L < CLASSES) out[(size_t)v * CLASSES + L] = fin(logit - ls);
}

extern "C" void kernel_launch(void* const* d_in, const int* in_sizes, int n_in,
                              void* d_out, int out_size, void* d_ws, size_t ws_size,
                              hipStream_t stream) {
  const void* x   = d_in[0];
  const int* ei   = (const int*)d_in[1];
  const void* Wl1 = d_in[2];
  const void* Wr1 = d_in[3];
  const void* a1  = d_in[4];
  const void* b1  = d_in[5];
  const void* Wl2 = d_in[6];
  const void* Wr2 = d_in[7];
  const void* a2  = d_in[8];
  const void* b2  = d_in[9];
  const void* W3  = d_in[10];
  const void* b3  = d_in[11];
  const void* W4  = d_in[12];
  const void* b4  = d_in[13];
  float* out = (float*)d_out;

  char* ws = (char*)d_ws;
  size_t off = 0;
  auto alloc = [&](size_t bytes) { size_t o = off; off += (bytes + 255) & ~(size_t)255; return o; };
  int* flag       = (int*)(ws + alloc(256));
  int* row_start  = (int*)(ws + alloc((size_t)(N_NODES + 1) * 4));
  int* counts     = (int*)(ws + alloc((size_t)N_NODES * 4));
  int* cursor     = (int*)(ws + alloc((size_t)N_NODES * 4));
  int* bsum       = (int*)(ws + alloc(64 * 4));
  int* csr_src    = (int*)(ws + alloc((size_t)EN_TOT * 4));
  unsigned short* Bp  = (unsigned short*)(ws + alloc((size_t)HC * HC * 2));
  unsigned short* Bp3 = (unsigned short*)(ws + alloc((size_t)HC * 32 * 2));   // 24 KB
  unsigned short* B0  = (unsigned short*)(ws + alloc((size_t)N_NODES * HC * 2));
  unsigned short* B1  = (unsigned short*)(ws + alloc((size_t)N_NODES * HC * 2));
  float* H3       = (float*)B0;  // reuses B0 after it's dead
  (void)in_sizes; (void)n_in;

  if (ws_size < off) {
    k_sentinel<<<(out_size + 255) / 256, 256, 0, stream>>>(out, out_size);
    return;
  }

  const int SCAN_BLOCKS = (N_NODES + 1023) / 1024;   // 49
  const int GEMM_BLOCKS = (N_NODES + 63) / 64;       // 782

  k_detect<<<1, 64, 0, stream>>>((const unsigned short*)x, flag);

  // --- CSR by dst ---
  k_zero2<<<(N_NODES + 255) / 256, 256, 0, stream>>>(counts, cursor, N_NODES);
  k_count<<<(EN_TOT + 255) / 256, 256, 0, stream>>>(ei, counts);
  k_scan1<<<SCAN_BLOCKS, 1024, 0, stream>>>(counts, row_start, bsum);
  k_scan2<<<1, 64, 0, stream>>>(bsum, SCAN_BLOCKS);
  k_scan3<<<SCAN_BLOCKS, 1024, 0, stream>>>(row_start, bsum);
  k_fill<<<(EN_TOT + 255) / 256, 256, 0, stream>>>(ei, row_start, cursor, csr_src);

  // --- layer 1 (K=128, A may be fp32) ---
  k_pack_b<<<(F_IN * HC + 255) / 256, 256, 0, stream>>>(Wl1, Bp, F_IN, 24, flag);
  k_gemm<4, 1><<<GEMM_BLOCKS, 256, 0, stream>>>(x, Bp, B0, flag);
  k_pack_b<<<(F_IN * HC + 255) / 256, 256, 0, stream>>>(Wr1, Bp, F_IN, 24, flag);
  k_gemm<4, 1><<<GEMM_BLOCKS, 256, 0, stream>>>(x, Bp, B1, flag);
  k_edge<<<N_NODES, 64, 0, stream>>>(B0, B1, row_start, csr_src, a1, b1, B1, flag);

  // --- layer 2 (K=384, A is bf16) ---
  k_pack_b<<<(HC * HC + 255) / 256, 256, 0, stream>>>(Wl2, Bp, HC, 24, flag);
  k_gemm<12, 0><<<GEMM_BLOCKS, 256, 0, stream>>>(B1, Bp, B0, flag);
  k_pack_b<<<(HC * HC + 255) / 256, 256, 0, stream>>>(Wr2, Bp, HC, 24, flag);
  k_gemm<12, 0><<<GEMM_BLOCKS, 256, 0, stream>>>(B1, Bp, B1, flag);
  k_edge<<<N_NODES, 64, 0, stream>>>(B0, B1, row_start, csr_src, a2, b2, B1, flag);

  // --- MLP head + log_softmax ---
  k_pack_b<<<(HC * 32 + 255) / 256, 256, 0, stream>>>(W3, Bp3, HC, 2, flag);
  k_mlp1_mfma<<<N_NODES / 16, 64, 0, stream>>>(B1, Bp3, b3, H3, flag);
  k_mlp2<<<N_NODES, 64, 0, stream>>>(H3, W4, b4, out, flag);
}